// Round 9
// baseline (238.871 us; speedup 1.0000x reference)
//
#include <hip/hip_runtime.h>

// Problem constants (from reference):
//   x: [B=32, C=1, F=257, T=4096] float32 log-magnitude spectrogram
//   SHIFT_BINS = 20.0 / (16000/512) = 0.64  -> f_low = f, f_high = f+1
//   out[b,f,t] = log10((1-a)*10^x[b,f,t] + a*10^x[b,f+1,t] + 1e-8), f < 256
//   out[b,256,t] = log10(1e-8)   (valid mask false at the top bin)
//
// Round 9: steady-state pipeline via LDS ring + global_load_lds (T3 2-phase
// minimum, the guide-verified pattern). R7/R8 proved hand-split asm
// load->vmcnt over compiler-allocated VGPRs is unsound (register churn
// between issue and wait corrupts data). global_load_lds has NO destination
// register -> no lifetime hazard; raw s_barrier + counted asm vmcnt sustains
// loads in flight across barriers (m201-proven in plain HIP).
// Each block: 16-row band, ring of 4 LDS row-slots. Task r: DMA row r+2,
// vmcnt(4) [in-order loads: <=4 pending => slot r+1 landed, stores ignored],
// barrier, compute row r from carried p=10^row(r) regs + slot r+1, store NT.
// Ring-4 + 1 barrier/task is race-free (DMA target >=2 slots from any reader).
#define B_DIM 32
#define F_DIM 257
#define T_DIM 4096
#define EPS_F 1e-8f

#define LOG2_10  3.32192809488736234787f
#define LOG10_2  0.30102999566398119521f

#define BAND   16                      // output rows per block
#define NBANDS 16                      // 256 / BAND
#define NBLK   (B_DIM * NBANDS)        // 512 blocks = 2/CU, one generation
#define SLOTS  4                       // LDS ring slots (16 KB each)

typedef float f32x4 __attribute__((ext_vector_type(4)));
typedef __attribute__((address_space(1))) void* gvoidp;
typedef __attribute__((address_space(3))) void* svoidp;

__device__ __forceinline__ float pow10_fast(float v) {
    // 10^v = 2^(v * log2(10)); v_exp_f32 is ~1 ulp — far under the absmax threshold
    return __builtin_amdgcn_exp2f(v * LOG2_10);
}
__device__ __forceinline__ float log10_fast(float v) {
    return __builtin_amdgcn_logf(v) * LOG10_2;  // v_log_f32 is log2
}

__global__ __launch_bounds__(256) void freq_shift_kernel(
        const float* __restrict__ x, float* __restrict__ out) {
    __shared__ float lds[SLOTS][T_DIM];          // 64 KB -> 2 blocks/CU

    // XCD-chunked bijective swizzle (512 % 8 == 0): consecutive ids (which
    // share band-boundary rows) stay on one XCD's L2.
    const int bid = blockIdx.x;
    const int id  = (bid & 7) * (NBLK / 8) + (bid >> 3);
    const int b   = id >> 4;                     // 16 bands per batch image
    const int fb  = id & (NBANDS - 1);
    const int f0  = fb * BAND;
    const int tid = threadIdx.x;
    const int wid = tid >> 6;                    // wave id (4 waves)

    const float* __restrict__ xb = x   + ((long long)(b * F_DIM + f0)) * T_DIM;
    float* __restrict__       ob = out + ((long long)(b * F_DIM + f0)) * T_DIM;

    // DMA band-row k (k=0..BAND) into LDS slot k%4. Dest rule (guide §5):
    // wave-uniform base + lane*16B; global source is per-lane.
    auto stage = [&](int k) {
        const float* src = xb + (long long)k * T_DIM + (tid << 2);
#pragma unroll
        for (int j = 0; j < 4; ++j) {
            float* dst = &lds[k & 3][j * 1024 + wid * 256];
            __builtin_amdgcn_global_load_lds((gvoidp)(src + j * 1024),
                                             (svoidp)dst, 16, 0, 0);
        }
    };

    // ---- prologue: rows f0, f0+1 in flight; wait slot0 (4 younger = slot1)
    stage(0);
    stage(1);
    asm volatile("s_waitcnt vmcnt(4)" ::: "memory");
    __builtin_amdgcn_sched_barrier(0);
    __builtin_amdgcn_s_barrier();

    // carried p = 10^row(f0): pow10 computed ONCE per element across tasks
    f32x4 p[4];
    {
        const f32x4* s0 = (const f32x4*)&lds[0][0];
#pragma unroll
        for (int j = 0; j < 4; ++j) {
            const f32x4 v = s0[j * 256 + tid];
            p[j].x = pow10_fast(v.x); p[j].y = pow10_fast(v.y);
            p[j].z = pow10_fast(v.z); p[j].w = pow10_fast(v.w);
        }
    }

#pragma unroll
    for (int r = 0; r < BAND; ++r) {
        // keep the NEXT row's DMA in flight under this task's compute
        if (r + 2 <= BAND) {
            stage(r + 2);
            // in-order loads: <=4 outstanding => all of batch r+1 landed
            // (pending stores only make this wait stricter, never unsafe)
            asm volatile("s_waitcnt vmcnt(4)" ::: "memory");
        } else {
            asm volatile("s_waitcnt vmcnt(0)" ::: "memory");
        }
        __builtin_amdgcn_sched_barrier(0);
        __builtin_amdgcn_s_barrier();

        // Reproduce reference fp32 alpha: target = fl(f+0.64f); alpha = target-f
        // (exact subtraction by Sterbenz; matches jnp float32 weak-typed arith)
        const float ff    = (float)(f0 + r);
        const float alpha = (ff + 0.64f) - ff;
        const float beta  = 1.0f - alpha;

        const f32x4* sn = (const f32x4*)&lds[(r + 1) & 3][0];
        f32x4* orow = (f32x4*)(ob + (long long)r * T_DIM);
#pragma unroll
        for (int j = 0; j < 4; ++j) {
            const f32x4 v = sn[j * 256 + tid];
            f32x4 pn;
            pn.x = pow10_fast(v.x); pn.y = pow10_fast(v.y);
            pn.z = pow10_fast(v.z); pn.w = pow10_fast(v.w);
            f32x4 res;
            res.x = log10_fast(beta * p[j].x + alpha * pn.x + EPS_F);
            res.y = log10_fast(beta * p[j].y + alpha * pn.y + EPS_F);
            res.z = log10_fast(beta * p[j].z + alpha * pn.z + EPS_F);
            res.w = log10_fast(beta * p[j].w + alpha * pn.w + EPS_F);
            // out is write-once, never re-read: NT store keeps cache lines
            // free for the shared boundary-row reads.
            __builtin_nontemporal_store(res, orow + j * 256 + tid);
            p[j] = pn;                 // static index after unroll (rule #20)
        }
    }

    // top bin f=256: log10(0 + 1e-8) constant, written by the last band
    if (fb == NBANDS - 1) {
        const float cv = log10_fast(EPS_F);
        f32x4 vv; vv.x = cv; vv.y = cv; vv.z = cv; vv.w = cv;
        f32x4* orow = (f32x4*)(ob + (long long)BAND * T_DIM);
#pragma unroll
        for (int j = 0; j < 4; ++j)
            __builtin_nontemporal_store(vv, orow + j * 256 + tid);
    }
}

extern "C" void kernel_launch(void* const* d_in, const int* in_sizes, int n_in,
                              void* d_out, int out_size, void* d_ws, size_t ws_size,
                              hipStream_t stream) {
    const float* x = (const float*)d_in[0];
    float* out = (float*)d_out;
    // 512 blocks x 256 threads: 2 blocks/CU, whole grid co-resident, each
    // block streams 16 row-tasks through a 4-slot LDS ring.
    dim3 grid(NBLK);
    dim3 block(256);
    freq_shift_kernel<<<grid, block, 0, stream>>>(x, out);
}